// Round 16
// baseline (62.335 us; speedup 1.0000x reference)
//
#include <hip/hip_runtime.h>

typedef _Float16 f16;
typedef _Float16 f16x8 __attribute__((ext_vector_type(8)));
typedef float f32x4 __attribute__((ext_vector_type(4)));

#define BD 512  // D == H == 512
#define SBAR() __builtin_amdgcn_sched_barrier(0)

// asm-pinned 16B global load (compiler does NOT track these; every consumer
// must sit below an explicit s_waitcnt + sched_barrier(0) fence — rule #18)
__device__ __forceinline__ float4 gload16(const void* p) {
  float4 r;
  asm volatile("global_load_dwordx4 %0, %1, off" : "=v"(r) : "v"(p) : "memory");
  return r;
}
__device__ __forceinline__ float gload4(const void* p) {
  float r;
  asm volatile("global_load_dword %0, %1, off" : "=v"(r) : "v"(p) : "memory");
  return r;
}
__device__ __forceinline__ f16x8 cvt8(float4 a, float4 b) {
  f16x8 h;
  h[0]=(f16)a.x; h[1]=(f16)a.y; h[2]=(f16)a.z; h[3]=(f16)a.w;
  h[4]=(f16)b.x; h[5]=(f16)b.y; h[6]=(f16)b.z; h[7]=(f16)b.w;
  return h;
}
__device__ __forceinline__ float sq4(float4 v) {
  return v.x*v.x + v.y*v.y + v.z*v.z + v.w*v.w;
}

// ---- fused GEMM: out = relu(A @ W^T + bias). 64x64 tile, 4 waves 32x32, BK=64,
// ring-2 LDS, reg-staged f32->f16 operands (asm loads, depth-2, counted vmcnt).
// PICK0: A = x (f32), W = projW; by<2 blocks also compute novelty partials.
// PICK1/2: A = f16 activation, W = opsW[ia/ib]. PICK2 block(0,0) finalizes novelty.
template <int PICK, int OUTF16>
__global__ __launch_bounds__(256, 2) void gemm_fused_kernel(
    const void* __restrict__ Asrc, const float* __restrict__ Wsrc,
    const float* __restrict__ memf, const float* __restrict__ ball,
    const float* __restrict__ logits, void* __restrict__ Out,
    float* __restrict__ novPart, float* __restrict__ novOut) {
  __shared__ __align__(16) char lds[32768];   // ring-2: per buf 8KB A + 8KB B; nov overlay
  __shared__ float xn[64];
  __shared__ float mn[32];
  __shared__ float red[4];

  const int t = threadIdx.x, l = t & 63, w = t >> 6;
  const int wr = w >> 1, wc = w & 1;          // wave tile: rows wr*32, cols wc*32
  const int lr = l & 15, lk = l >> 4;
  const int bx = blockIdx.x, by = blockIdx.y;
  const int rowBase = bx * 64, colBase = by * 64;

  // routing (PICK>0): top-2 of 3 logits, softmax-monotonic, ties -> lower idx
  int widx = 0;
  if (PICK > 0) {
    float l0 = logits[0], l1 = logits[1], l2 = logits[2];
    int ia = 0; float ba = l0;
    if (l1 > ba) { ba = l1; ia = 1; }
    if (l2 > ba) { ba = l2; ia = 2; }
    if (PICK == 1) {
      widx = ia;
    } else {
      int ib = 0; float bb2 = -3.4e38f;
      if (ia != 0)             { bb2 = l0; ib = 0; }
      if (ia != 1 && l1 > bb2) { bb2 = l1; ib = 1; }
      if (ia != 2 && l2 > bb2) { bb2 = l2; ib = 2; }
      widx = ib;
    }
  }
  const float* Wf = Wsrc + (size_t)widx * 262144;
  const float* bias = ball + widx * BD;

  // pinned bias preloads (consumed in epilogue, after the final vmcnt(0) fence)
  float bbv[2];
  bbv[0] = gload4(&bias[colBase + wc * 32 + lr]);
  bbv[1] = gload4(&bias[colBase + wc * 32 + 16 + lr]);

  // novelty finalize (GEMM3 only; novPart complete since GEMM1 finished)
  if (PICK == 2 && bx == 0 && by == 0 && w == 0) {
    float s = novPart[l] + novPart[l + 64] + novPart[l + 128] + novPart[l + 192];
    #pragma unroll
    for (int off = 32; off; off >>= 1) s += __shfl_down(s, off, 64);
    if (l == 0) novOut[0] = fminf(1.5f, s * (1.0f / (8192.0f * 50.0f)));
  }
  asm volatile("s_waitcnt vmcnt(0)" ::: "memory");   // clean counter baseline
  SBAR();

  // ================= novelty phase (PICK0, by<2): 64 rows x 32 mems =================
  if (PICK == 0 && by < 2) {
    const float* xf = (const float*)Asrc;
    const int xrow = t >> 2;            // 0..63 (4 thr/row)
    const int xc0 = (t * 2) & 7;        // chunk pair xc0, xc0+1
    const int mrow = t >> 3;            // 0..31 (8 thr/row)
    const int mch = t & 7;
    const int mglob = by * 32 + mrow;
    const int msrcRow = (mglob < 50) ? mglob : 49;
    const bool mvalid = (mglob < 50);

    float4 rx[2][4], rm[2][2];
    f32x4 nacc0 = (f32x4){0.f,0.f,0.f,0.f};
    f32x4 nacc1 = (f32x4){0.f,0.f,0.f,0.f};
    float xsq = 0.f, msq = 0.f;

    auto novIssue = [&](int slot, int cc) {
      const float* xs = xf + (size_t)(rowBase + xrow) * BD + cc * 64 + xc0 * 8;
      rx[slot][0] = gload16(xs);      rx[slot][1] = gload16(xs + 4);
      rx[slot][2] = gload16(xs + 8);  rx[slot][3] = gload16(xs + 12);
      const float* ms = memf + (size_t)msrcRow * BD + cc * 64 + mch * 8;
      rm[slot][0] = gload16(ms);      rm[slot][1] = gload16(ms + 4);
    };

    novIssue(0, 0);
    novIssue(1, 1);
    #pragma unroll
    for (int cc = 0; cc < 8; ++cc) {
      if (cc < 7) asm volatile("s_waitcnt vmcnt(6)" ::: "memory");
      else        asm volatile("s_waitcnt vmcnt(0)" ::: "memory");
      SBAR();                                      // rule #18: pin reg-uses below wait
      const int sl = cc & 1;
      f16* XC = (f16*)(lds + sl * 12288);          // 64 x 64 f16
      f16* MC = (f16*)(lds + sl * 12288 + 8192);   // 32 x 64 f16
      xsq += sq4(rx[sl][0]) + sq4(rx[sl][1]) + sq4(rx[sl][2]) + sq4(rx[sl][3]);
      *(f16x8*)&XC[xrow * 64 + ((xc0 ^ (xrow & 7)) << 3)]       = cvt8(rx[sl][0], rx[sl][1]);
      *(f16x8*)&XC[xrow * 64 + (((xc0 + 1) ^ (xrow & 7)) << 3)] = cvt8(rx[sl][2], rx[sl][3]);
      f16x8 mh = cvt8(rm[sl][0], rm[sl][1]);
      if (mvalid) {
        msq += sq4(rm[sl][0]) + sq4(rm[sl][1]);
      } else {
        #pragma unroll
        for (int j = 0; j < 8; ++j) mh[j] = (f16)0.f;
      }
      *(f16x8*)&MC[mrow * 64 + ((mch ^ (mrow & 7)) << 3)] = mh;
      asm volatile("s_waitcnt lgkmcnt(0)" ::: "memory");
      SBAR();
      __builtin_amdgcn_s_barrier();
      if (cc + 2 < 8) novIssue(sl, cc + 2);
      #pragma unroll
      for (int kk = 0; kk < 64; kk += 32) {
        const int ch = (kk >> 3) + lk;
        const int ar = w * 16 + lr;
        f16x8 af = *(const f16x8*)&XC[ar * 64 + ((ch ^ (ar & 7)) << 3)];
        const int br0 = lr;
        f16x8 bf0 = *(const f16x8*)&MC[br0 * 64 + ((ch ^ (br0 & 7)) << 3)];
        nacc0 = __builtin_amdgcn_mfma_f32_16x16x32_f16(af, bf0, nacc0, 0, 0, 0);
        const int br1 = 16 + lr;
        f16x8 bf1 = *(const f16x8*)&MC[br1 * 64 + ((ch ^ (br1 & 7)) << 3)];
        nacc1 = __builtin_amdgcn_mfma_f32_16x16x32_f16(af, bf1, nacc1, 0, 0, 0);
      }
    }
    xsq += __shfl_xor(xsq, 1, 64); xsq += __shfl_xor(xsq, 2, 64);
    if ((l & 3) == 0) xn[t >> 2] = xsq;
    msq += __shfl_xor(msq, 1, 64); msq += __shfl_xor(msq, 2, 64); msq += __shfl_xor(msq, 4, 64);
    if ((l & 7) == 0) mn[t >> 3] = msq;
    __syncthreads();
    float local = 0.f;
    {
      const int m0 = by * 32 + lr;
      if (m0 < 50) {
        #pragma unroll
        for (int j = 0; j < 4; ++j) {
          const int row = w * 16 + lk * 4 + j;       // C/D: row=(lane>>4)*4+j
          float d = xn[row] - 2.f * nacc0[j] + mn[lr];
          local += sqrtf(fmaxf(d, 0.f));
        }
      }
      const int m1 = by * 32 + 16 + lr;
      if (m1 < 50) {
        #pragma unroll
        for (int j = 0; j < 4; ++j) {
          const int row = w * 16 + lk * 4 + j;
          float d = xn[row] - 2.f * nacc1[j] + mn[16 + lr];
          local += sqrtf(fmaxf(d, 0.f));
        }
      }
    }
    #pragma unroll
    for (int off = 32; off; off >>= 1) local += __shfl_down(local, off, 64);
    if (l == 0) red[w] = local;
    __syncthreads();
    if (t == 0) novPart[by * 128 + bx] = red[0] + red[1] + red[2] + red[3];
    __syncthreads();
    asm volatile("s_waitcnt vmcnt(0)" ::: "memory");  // drain novPart store
    SBAR();
  }

  // ================= main GEMM pipeline =================
  const int arow = t >> 2;            // staging row 0..63 (4 thr/row, 32B f16 each)
  const int ac0 = (t * 2) & 7;        // chunk pair
  float4 ra[2][4], rb[2][4];

  auto issue = [&](int slot, int tt) {
    const int kt = tt * 64;
    if constexpr (PICK == 0) {
      const float* as = (const float*)Asrc + (size_t)(rowBase + arow) * BD + kt + ac0 * 8;
      ra[slot][0] = gload16(as);      ra[slot][1] = gload16(as + 4);
      ra[slot][2] = gload16(as + 8);  ra[slot][3] = gload16(as + 12);
    } else {
      const f16* as = (const f16*)Asrc + (size_t)(rowBase + arow) * BD + kt + ac0 * 8;
      ra[slot][0] = gload16(as);      ra[slot][1] = gload16(as + 8);
    }
    const float* bs = Wf + (size_t)(colBase + arow) * BD + kt + ac0 * 8;
    rb[slot][0] = gload16(bs);      rb[slot][1] = gload16(bs + 4);
    rb[slot][2] = gload16(bs + 8);  rb[slot][3] = gload16(bs + 12);
  };

  f32x4 acc[2][2];
  #pragma unroll
  for (int m = 0; m < 2; ++m)
    #pragma unroll
    for (int n = 0; n < 2; ++n) acc[m][n] = (f32x4){0.f, 0.f, 0.f, 0.f};

  issue(0, 0);
  issue(1, 1);
  #pragma unroll
  for (int t8 = 0; t8 < 8; ++t8) {
    if (t8 < 7) {
      if constexpr (PICK == 0) asm volatile("s_waitcnt vmcnt(8)" ::: "memory");
      else                     asm volatile("s_waitcnt vmcnt(6)" ::: "memory");
    } else {
      asm volatile("s_waitcnt vmcnt(0)" ::: "memory");
    }
    SBAR();                                       // rule #18 fence
    const int sl = t8 & 1;
    f16* Ab = (f16*)(lds + sl * 16384);
    f16* Bb = (f16*)(lds + sl * 16384 + 8192);
    if constexpr (PICK == 0) {
      *(f16x8*)&Ab[arow * 64 + ((ac0 ^ (arow & 7)) << 3)]       = cvt8(ra[sl][0], ra[sl][1]);
      *(f16x8*)&Ab[arow * 64 + (((ac0 + 1) ^ (arow & 7)) << 3)] = cvt8(ra[sl][2], ra[sl][3]);
    } else {
      *(f16x8*)&Ab[arow * 64 + ((ac0 ^ (arow & 7)) << 3)]       = *(f16x8*)&ra[sl][0];
      *(f16x8*)&Ab[arow * 64 + (((ac0 + 1) ^ (arow & 7)) << 3)] = *(f16x8*)&ra[sl][1];
    }
    *(f16x8*)&Bb[arow * 64 + ((ac0 ^ (arow & 7)) << 3)]       = cvt8(rb[sl][0], rb[sl][1]);
    *(f16x8*)&Bb[arow * 64 + (((ac0 + 1) ^ (arow & 7)) << 3)] = cvt8(rb[sl][2], rb[sl][3]);
    asm volatile("s_waitcnt lgkmcnt(0)" ::: "memory");
    SBAR();
    __builtin_amdgcn_s_barrier();                 // tile t8 in LDS (all waves)
    if (t8 + 2 < 8) issue(sl, t8 + 2);            // after barrier: buf sl free of readers
    #pragma unroll
    for (int kk = 0; kk < 64; kk += 32) {
      const int ch = (kk >> 3) + lk;
      f16x8 af[2], bf[2];
      #pragma unroll
      for (int m = 0; m < 2; ++m) {
        const int row = wr * 32 + m * 16 + lr;
        af[m] = *(const f16x8*)&Ab[row * 64 + ((ch ^ (row & 7)) << 3)];
      }
      #pragma unroll
      for (int n = 0; n < 2; ++n) {
        const int row = wc * 32 + n * 16 + lr;
        bf[n] = *(const f16x8*)&Bb[row * 64 + ((ch ^ (row & 7)) << 3)];
      }
      __builtin_amdgcn_s_setprio(1);
      #pragma unroll
      for (int m = 0; m < 2; ++m)
        #pragma unroll
        for (int n = 0; n < 2; ++n)
          acc[m][n] = __builtin_amdgcn_mfma_f32_16x16x32_f16(af[m], bf[n], acc[m][n], 0, 0, 0);
      __builtin_amdgcn_s_setprio(0);
    }
  }

  // epilogue: bias + relu, store (bbv regs valid: vmcnt(0)+SBAR above)
  #pragma unroll
  for (int n = 0; n < 2; ++n) {
    const int col = colBase + wc * 32 + n * 16 + lr;
    #pragma unroll
    for (int m = 0; m < 2; ++m) {
      #pragma unroll
      for (int j = 0; j < 4; ++j) {
        const int rowg = rowBase + wr * 32 + m * 16 + lk * 4 + j;
        float v = fmaxf(acc[m][n][j] + bbv[n], 0.f);
        if (OUTF16) ((f16*)Out)[(size_t)rowg * BD + col] = (f16)v;
        else        ((float*)Out)[(size_t)rowg * BD + col] = v;
      }
    }
  }
}

extern "C" void kernel_launch(void* const* d_in, const int* in_sizes, int n_in,
                              void* d_out, int out_size, void* d_ws, size_t ws_size,
                              hipStream_t stream) {
  const float* x      = (const float*)d_in[0];   // [8192,512]
  const float* memf   = (const float*)d_in[1];   // [50,512]
  const float* logits = (const float*)d_in[2];   // [3]
  const float* projW  = (const float*)d_in[3];   // [512,512]
  const float* projB  = (const float*)d_in[4];   // [512]
  const float* opsW   = (const float*)d_in[5];   // [3,512,512]
  const float* opsB   = (const float*)d_in[6];   // [3,512]
  float* out = (float*)d_out;                    // [8192*512 + 1]

  char* ws = (char*)d_ws;
  f16*   g0      = (f16*)(ws);                // 8 MB
  f16*   h1      = (f16*)(ws + 8388608);      // 8 MB
  float* novPart = (float*)(ws + 16777216);   // 1 KB (256 floats)

  // layer 1 (+ novelty partials): g0 = relu(x @ projW^T + projB)
  gemm_fused_kernel<0, 1><<<dim3(128, 8), 256, 0, stream>>>(
      (const void*)x, projW, memf, projB, logits, (void*)g0, novPart, out + 4194304);
  // layer 2: h1 = relu(g0 @ Wa^T + ba)
  gemm_fused_kernel<1, 1><<<dim3(128, 8), 256, 0, stream>>>(
      (const void*)g0, opsW, memf, opsB, logits, (void*)h1, novPart, out + 4194304);
  // layer 3 (+ novelty finalize): out = relu(h1 @ Wb^T + bb)
  gemm_fused_kernel<2, 0><<<dim3(128, 8), 256, 0, stream>>>(
      (const void*)h1, opsW, memf, opsB, logits, (void*)out, novPart, out + 4194304);
}

// Round 18
// 48.378 us; speedup vs baseline: 1.2885x; 1.2885x over previous
//
#include <hip/hip_runtime.h>

typedef _Float16 f16;
typedef _Float16 f16x8 __attribute__((ext_vector_type(8)));
typedef float f32x4 __attribute__((ext_vector_type(4)));

#define BD 512  // D == H == 512

// async global->LDS, 16B per lane. LDS dest is wave-uniform base + lane*16.
__device__ __forceinline__ void llds16(const void* g, void* l) {
  __builtin_amdgcn_global_load_lds(
      (const __attribute__((address_space(1))) unsigned int*)g,
      (__attribute__((address_space(3))) unsigned int*)l,
      16, 0, 0);
}
__device__ __forceinline__ f16x8 cvt8(float4 a, float4 b) {
  f16x8 h;
  h[0]=(f16)a.x; h[1]=(f16)a.y; h[2]=(f16)a.z; h[3]=(f16)a.w;
  h[4]=(f16)b.x; h[5]=(f16)b.y; h[6]=(f16)b.z; h[7]=(f16)b.w;
  return h;
}

// ---- prep: W fp32->f16 (blocks 0..511) + mem fp32->f16 zero-padded (512..527) ----
__global__ __launch_bounds__(256) void prep_kernel(
    const float* __restrict__ projW, const float* __restrict__ opsW,
    const float* __restrict__ memf, f16* __restrict__ wh,
    f16* __restrict__ memh) {
  const int bid = blockIdx.x, t = threadIdx.x;
  if (bid < 512) {
    const int e = (bid * 256 + t) * 8;
    const float* s = (e < 262144) ? (projW + e) : (opsW + (e - 262144));
    float4 v0 = ((const float4*)s)[0];
    float4 v1 = ((const float4*)s)[1];
    *(f16x8*)&wh[e] = cvt8(v0, v1);
  } else {
    const int e = ((bid - 512) * 256 + t) * 8;   // 16*256*8 = 32768 = 64*512
    const int row = e >> 9;
    f16x8 h;
    if (row < 50) {
      float4 v0 = ((const float4*)(memf + e))[0];
      float4 v1 = ((const float4*)(memf + e))[1];
      h = cvt8(v0, v1);
    } else {
      #pragma unroll
      for (int j = 0; j < 8; ++j) h[j] = (f16)0.f;
    }
    *(f16x8*)&memh[e] = h;
  }
}

// ---- GEMM1': g0 = relu(x @ projW^T + b), A = x f32 staged, BK=32, ring-3.
// by==0 blocks additionally compute novelty partials vs memh (64 padded rows).
__global__ __launch_bounds__(256, 2) void gemm1_nov_kernel(
    const float* __restrict__ x, const f16* __restrict__ wh,
    const f16* __restrict__ memh, const float* __restrict__ projB,
    f16* __restrict__ g0, float* __restrict__ novPart) {
  __shared__ __align__(16) char lds[3 * 16384];  // per buf: A 8KB f32 | B 4KB | M 4KB
  __shared__ float red[4];

  const int t = threadIdx.x, l = t & 63, w = t >> 6;
  const int wr = w >> 1, wc = w & 1;          // wave tile: rows wr*32, cols wc*32
  const int lr = l & 15, lk = l >> 4;
  const int rowBase = blockIdx.x * 64, colBase = blockIdx.y * 64;
  const bool NOV = (blockIdx.y == 0);

  // staging thread mapping
  const int aRow = (t * 16) >> 7;             // issue i adds 32 rows
  const int aCh  = ((t * 16) >> 4) & 7;
  const int bRow = (t * 16) >> 6;             // 0..63
  const int bCh  = ((t * 16) >> 4) & 3;

  auto stage = [&](int buf, int kt) {
    char* base = lds + buf * 16384;
    #pragma unroll
    for (int i = 0; i < 2; ++i) {             // A: 64r x 32 f32 = 8 KB
      const int row = aRow + i * 32;
      llds16(x + (size_t)(rowBase + row) * BD + kt + ((aCh ^ (row & 7)) * 4),
             base + i * 4096 + w * 1024);
    }
    llds16(wh + (size_t)(colBase + bRow) * BD + kt + ((bCh ^ (bRow & 3)) * 8),
           base + 8192 + w * 1024);           // B: 64r x 32 f16 = 4 KB
    if (NOV)
      llds16(memh + (size_t)bRow * BD + kt + ((bCh ^ (bRow & 3)) * 8),
             base + 12288 + w * 1024);        // M: 64r x 32 f16 = 4 KB
  };

  f32x4 acc[2][2], nacc[4];
  #pragma unroll
  for (int m = 0; m < 2; ++m)
    #pragma unroll
    for (int n = 0; n < 2; ++n) acc[m][n] = (f32x4){0.f,0.f,0.f,0.f};
  #pragma unroll
  for (int q = 0; q < 4; ++q) nacc[q] = (f32x4){0.f,0.f,0.f,0.f};
  float xsq[4] = {0.f, 0.f, 0.f, 0.f};
  float msq = 0.f;

  // read f32 A-frag for row r (16B-chunk XOR swizzle; chunks read independently)
  auto readA = [&](const float* Ab, int r) -> f16x8 {
    float4 r0 = *(const float4*)&Ab[r * 32 + (((2 * lk) ^ (r & 7)) << 2)];
    float4 r1 = *(const float4*)&Ab[r * 32 + (((2 * lk + 1) ^ (r & 7)) << 2)];
    return cvt8(r0, r1);
  };

  auto compute = [&](int buf) {
    const float* Ab = (const float*)(lds + buf * 16384);
    const f16* Bb = (const f16*)(lds + buf * 16384 + 8192);
    const f16* Mb = (const f16*)(lds + buf * 16384 + 12288);
    f16x8 af[2], bf[2];
    #pragma unroll
    for (int m = 0; m < 2; ++m) af[m] = readA(Ab, wr * 32 + m * 16 + lr);
    #pragma unroll
    for (int n = 0; n < 2; ++n) {
      const int row = wc * 32 + n * 16 + lr;
      bf[n] = *(const f16x8*)&Bb[row * 32 + ((lk ^ (row & 3)) << 3)];
    }
    __builtin_amdgcn_s_setprio(1);
    #pragma unroll
    for (int m = 0; m < 2; ++m)
      #pragma unroll
      for (int n = 0; n < 2; ++n)
        acc[m][n] = __builtin_amdgcn_mfma_f32_16x16x32_f16(af[m], bf[n], acc[m][n], 0, 0, 0);
    __builtin_amdgcn_s_setprio(0);
    if (NOV) {
      // novelty: x rows 0..63 (4 frags; 2 reused from af) x mem rows w*16..+15
      const int mrow = w * 16 + lr;
      f16x8 mf = *(const f16x8*)&Mb[mrow * 32 + ((lk ^ (mrow & 3)) << 3)];
      #pragma unroll
      for (int j = 0; j < 8; ++j) { float f = (float)mf[j]; msq += f * f; }
      f16x8 aq[4];                            // static assignment (rule #20)
      if (wr == 0) {
        aq[0] = af[0]; aq[1] = af[1];
        aq[2] = readA(Ab, 32 + lr); aq[3] = readA(Ab, 48 + lr);
      } else {
        aq[0] = readA(Ab, lr); aq[1] = readA(Ab, 16 + lr);
        aq[2] = af[0]; aq[3] = af[1];
      }
      #pragma unroll
      for (int q = 0; q < 4; ++q) {
        #pragma unroll
        for (int j = 0; j < 8; ++j) { float f = (float)aq[q][j]; xsq[q] += f * f; }
        nacc[q] = __builtin_amdgcn_mfma_f32_16x16x32_f16(aq[q], mf, nacc[q], 0, 0, 0);
      }
    }
  };

  // ring-3, prefetch 2 tiles; counted vmcnt (NOV: 4 issues/step, else 3)
  stage(0, 0);
  stage(1, 32);
  #pragma unroll
  for (int tt = 0; tt < 16; ++tt) {
    if (NOV) {
      if (tt < 15) asm volatile("s_waitcnt vmcnt(4)" ::: "memory");
      else         asm volatile("s_waitcnt vmcnt(0)" ::: "memory");
    } else {
      if (tt < 15) asm volatile("s_waitcnt vmcnt(3)" ::: "memory");
      else         asm volatile("s_waitcnt vmcnt(0)" ::: "memory");
    }
    __builtin_amdgcn_s_barrier();            // tile tt fully in LDS (all waves)
    if (tt < 14) stage((tt + 2) % 3, (tt + 2) * 32);
    compute(tt % 3);
    asm volatile("s_waitcnt lgkmcnt(0)" ::: "memory");  // my ds_reads drained
  }

  // ---- novelty tail: row/mem norms in-register, sqrt-sum, per-block partial ----
  if (NOV) {
    msq += __shfl_xor(msq, 16, 64);
    msq += __shfl_xor(msq, 32, 64);          // all lanes: ||mem_{w*16+lr}||^2
    #pragma unroll
    for (int q = 0; q < 4; ++q) {
      xsq[q] += __shfl_xor(xsq[q], 16, 64);
      xsq[q] += __shfl_xor(xsq[q], 32, 64);  // all lanes: ||x_{q*16+lr}||^2
    }
    const int mm = w * 16 + lr;
    float local = 0.f;
    if (mm < 50) {
      #pragma unroll
      for (int j = 0; j < 4; ++j) {
        const int r16 = lk * 4 + j;          // C/D row-in-16 = (lane>>4)*4 + j
        #pragma unroll
        for (int q = 0; q < 4; ++q) {
          const float xs = __shfl(xsq[q], r16, 64);   // holder lane: lr == r16
          float d = xs - 2.f * nacc[q][j] + msq;
          local += sqrtf(fmaxf(d, 0.f));
        }
      }
    }
    #pragma unroll
    for (int off = 32; off; off >>= 1) local += __shfl_down(local, off, 64);
    if (l == 0) red[w] = local;
    __syncthreads();
    if (t == 0) novPart[blockIdx.x] = red[0] + red[1] + red[2] + red[3];
  }

  // epilogue: bias + relu, store f16
  #pragma unroll
  for (int n = 0; n < 2; ++n) {
    const int col = colBase + wc * 32 + n * 16 + lr;
    const float bbv = projB[col];
    #pragma unroll
    for (int m = 0; m < 2; ++m) {
      #pragma unroll
      for (int j = 0; j < 4; ++j) {
        const int rowg = rowBase + wr * 32 + m * 16 + lk * 4 + j;
        g0[(size_t)rowg * BD + col] = (f16)fmaxf(acc[m][n][j] + bbv, 0.f);
      }
    }
  }
}

// ---- GEMM2/3: out = relu(A @ W^T + bias), 64x64 tile, BK=64, ring-4 (r12-proven) ----
// PICK: 1 = ops_W[idx_a]; 2 = ops_W[idx_b] (also finalizes novelty at block(0,0))
// NOTE: Wall must point at the OPS weight table (wh + 262144) — r17's bug.
template <int PICK, int OUTF16>
__global__ __launch_bounds__(256, 2) void gemm_relu_kernel(
    const f16* __restrict__ A, const f16* __restrict__ Wall,
    const float* __restrict__ ball, const float* __restrict__ logits,
    void* __restrict__ Out, const float* __restrict__ novPart,
    float* __restrict__ novOut) {
  __shared__ __align__(16) char lds[4 * 16384];  // per buf: 8 KB A + 8 KB B

  const int t = threadIdx.x;
  const int l = t & 63;
  const int w = t >> 6;
  const int wr = w >> 1, wc = w & 1;
  const int lr = l & 15, lk = l >> 4;

  if (PICK == 2 && blockIdx.x == 0 && blockIdx.y == 0 && w == 0) {
    float s = novPart[l] + novPart[l + 64];      // 128 partials
    #pragma unroll
    for (int off = 32; off; off >>= 1) s += __shfl_down(s, off, 64);
    if (l == 0) novOut[0] = fminf(1.5f, s * (1.0f / (8192.0f * 50.0f)));
  }

  float l0 = logits[0], l1 = logits[1], l2 = logits[2];
  int ia = 0; float ba = l0;
  if (l1 > ba) { ba = l1; ia = 1; }
  if (l2 > ba) { ba = l2; ia = 2; }
  int widx;
  if (PICK == 1) {
    widx = ia;
  } else {
    int ib = 0; float bb2 = -3.4e38f;
    if (ia != 0)             { bb2 = l0; ib = 0; }
    if (ia != 1 && l1 > bb2) { bb2 = l1; ib = 1; }
    if (ia != 2 && l2 > bb2) { bb2 = l2; ib = 2; }
    widx = ib;
  }
  const f16* W = Wall + (size_t)widx * BD * BD;
  const float* bias = ball + widx * BD;

  const int rowBase = blockIdx.x * 64;
  const int colBase = blockIdx.y * 64;

  f32x4 acc[2][2];
  #pragma unroll
  for (int m = 0; m < 2; ++m)
    #pragma unroll
    for (int n = 0; n < 2; ++n) acc[m][n] = (f32x4){0.f, 0.f, 0.f, 0.f};

  auto stage = [&](int buf, int kt) {
    f16* Ab = (f16*)(lds + buf * 16384);
    f16* Bb = (f16*)(lds + buf * 16384 + 8192);
    #pragma unroll
    for (int i = 0; i < 2; ++i) {
      const int o = i * 4096 + t * 16;
      const int row = o >> 7;                // 128 B per row (64 f16)
      const int sch = ((o >> 4) & 7) ^ (row & 7);
      llds16(A + (size_t)(rowBase + row) * BD + kt + sch * 8,
             (char*)Ab + i * 4096 + w * 1024);
      llds16(W + (size_t)(colBase + row) * BD + kt + sch * 8,
             (char*)Bb + i * 4096 + w * 1024);
    }
  };

  auto compute = [&](int buf) {
    const f16* Ab = (const f16*)(lds + buf * 16384);
    const f16* Bb = (const f16*)(lds + buf * 16384 + 8192);
    #pragma unroll
    for (int kk = 0; kk < 64; kk += 32) {
      const int ch = (kk >> 3) + lk;
      f16x8 af[2], bf[2];
      #pragma unroll
      for (int m = 0; m < 2; ++m) {
        const int row = wr * 32 + m * 16 + lr;
        af[m] = *(const f16x8*)&Ab[row * 64 + ((ch ^ (row & 7)) << 3)];
      }
      #pragma unroll
      for (int n = 0; n < 2; ++n) {
        const int row = wc * 32 + n * 16 + lr;
        bf[n] = *(const f16x8*)&Bb[row * 64 + ((ch ^ (row & 7)) << 3)];
      }
      __builtin_amdgcn_s_setprio(1);
      #pragma unroll
      for (int m = 0; m < 2; ++m)
        #pragma unroll
        for (int n = 0; n < 2; ++n)
          acc[m][n] = __builtin_amdgcn_mfma_f32_16x16x32_f16(af[m], bf[n], acc[m][n], 0, 0, 0);
      __builtin_amdgcn_s_setprio(0);
    }
  };

  stage(0, 0);
  stage(1, 64);
  stage(2, 128);
  #pragma unroll
  for (int t8 = 0; t8 < 8; ++t8) {
    if (t8 < 6)       asm volatile("s_waitcnt vmcnt(8)" ::: "memory");
    else if (t8 == 6) asm volatile("s_waitcnt vmcnt(4)" ::: "memory");
    else              asm volatile("s_waitcnt vmcnt(0)" ::: "memory");
    __builtin_amdgcn_s_barrier();
    if (t8 < 5) stage((t8 + 3) & 3, (t8 + 3) * 64);
    compute(t8 & 3);
    asm volatile("s_waitcnt lgkmcnt(0)" ::: "memory");
  }

  #pragma unroll
  for (int n = 0; n < 2; ++n) {
    const int col = colBase + wc * 32 + n * 16 + lr;
    const float bbv = bias[col];
    #pragma unroll
    for (int m = 0; m < 2; ++m) {
      #pragma unroll
      for (int j = 0; j < 4; ++j) {
        const int rowg = rowBase + wr * 32 + m * 16 + lk * 4 + j;
        float v = fmaxf(acc[m][n][j] + bbv, 0.f);
        if (OUTF16) ((f16*)Out)[(size_t)rowg * BD + col] = (f16)v;
        else        ((float*)Out)[(size_t)rowg * BD + col] = v;
      }
    }
  }
}

extern "C" void kernel_launch(void* const* d_in, const int* in_sizes, int n_in,
                              void* d_out, int out_size, void* d_ws, size_t ws_size,
                              hipStream_t stream) {
  const float* x      = (const float*)d_in[0];   // [8192,512]
  const float* memf   = (const float*)d_in[1];   // [50,512]
  const float* logits = (const float*)d_in[2];   // [3]
  const float* projW  = (const float*)d_in[3];   // [512,512]
  const float* projB  = (const float*)d_in[4];   // [512]
  const float* opsW   = (const float*)d_in[5];   // [3,512,512]
  const float* opsB   = (const float*)d_in[6];   // [3,512]
  float* out = (float*)d_out;                    // [8192*512 + 1]

  char* ws = (char*)d_ws;
  f16*   g0      = (f16*)(ws);                // 8 MB
  f16*   h1      = (f16*)(ws + 8388608);      // 8 MB
  f16*   wh      = (f16*)(ws + 16777216);     // 2 MB: proj_W f16, then ops_W f16
  f16*   memh    = (f16*)(ws + 18874368);     // 64 KB (64x512 zero-padded)
  float* novPart = (float*)(ws + 18939904);   // 512 B (128 floats)

  prep_kernel<<<528, 256, 0, stream>>>(projW, opsW, memf, wh, memh);

  // G1': g0 = relu(x @ projW^T + projB); by==0 blocks emit novelty partials
  gemm1_nov_kernel<<<dim3(128, 8), 256, 0, stream>>>(x, wh, memh, projB, g0, novPart);
  // G2: h1 = relu(g0 @ Wa^T + ba)   — ops weight table starts at wh + 262144
  gemm_relu_kernel<1, 1><<<dim3(128, 8), 256, 0, stream>>>(
      g0, wh + 262144, opsB, logits, (void*)h1, novPart, out + 4194304);
  // G3: out = relu(h1 @ Wb^T + bb); also finalizes novelty scalar
  gemm_relu_kernel<2, 0><<<dim3(128, 8), 256, 0, stream>>>(
      h1, wh + 262144, opsB, logits, (void*)out, novPart, out + 4194304);
}

// Round 19
// 45.907 us; speedup vs baseline: 1.3578x; 1.0538x over previous
//
#include <hip/hip_runtime.h>

typedef _Float16 f16;
typedef _Float16 f16x8 __attribute__((ext_vector_type(8)));
typedef float f32x4 __attribute__((ext_vector_type(4)));

#define BD 512  // D == H == 512

// async global->LDS, 16B per lane. LDS dest is wave-uniform base + lane*16.
__device__ __forceinline__ void llds16(const void* g, void* l) {
  __builtin_amdgcn_global_load_lds(
      (const __attribute__((address_space(1))) unsigned int*)g,
      (__attribute__((address_space(3))) unsigned int*)l,
      16, 0, 0);
}
__device__ __forceinline__ f16x8 cvt8(float4 a, float4 b) {
  f16x8 h;
  h[0]=(f16)a.x; h[1]=(f16)a.y; h[2]=(f16)a.z; h[3]=(f16)a.w;
  h[4]=(f16)b.x; h[5]=(f16)b.y; h[6]=(f16)b.z; h[7]=(f16)b.w;
  return h;
}

// XCD co-location remap: all 8 col-blocks of a row-panel land on ONE XCD so the
// A panel is fetched from L3 once and L2-hits 7 times. lid%8 == XCD (HW round-robin).
__device__ __forceinline__ void remap_xcd(int lid, int& rowPanel, int& colPanel) {
  const int xcd = lid & 7;
  const int j = lid >> 3;                 // 0..127
  rowPanel = (j & 15) * 8 + xcd;          // 0..127, ≡ xcd (mod 8)
  colPanel = j >> 4;                      // 0..7
}

// ---- prep: pure streaming cvt. blocks: [0,2048) x->xh, [2048,2560) W->wh,
// [2560,2576) mem->memh (64 rows zero-padded) ----
__global__ __launch_bounds__(256) void prep_kernel(
    const float* __restrict__ x, const float* __restrict__ projW,
    const float* __restrict__ opsW, const float* __restrict__ memf,
    f16* __restrict__ xh, f16* __restrict__ wh, f16* __restrict__ memh) {
  const int bid = blockIdx.x, t = threadIdx.x;
  if (bid < 2048) {
    const int e = (bid * 256 + t) * 8;
    float4 v0 = ((const float4*)(x + e))[0];
    float4 v1 = ((const float4*)(x + e))[1];
    *(f16x8*)&xh[e] = cvt8(v0, v1);
  } else if (bid < 2560) {
    const int e = ((bid - 2048) * 256 + t) * 8;
    const float* s = (e < 262144) ? (projW + e) : (opsW + (e - 262144));
    float4 v0 = ((const float4*)s)[0];
    float4 v1 = ((const float4*)s)[1];
    *(f16x8*)&wh[e] = cvt8(v0, v1);
  } else {
    const int e = ((bid - 2560) * 256 + t) * 8;   // 32768 padded elems
    const int row = e >> 9;
    f16x8 h;
    if (row < 50) {
      float4 v0 = ((const float4*)(memf + e))[0];
      float4 v1 = ((const float4*)(memf + e))[1];
      h = cvt8(v0, v1);
    } else {
      #pragma unroll
      for (int j = 0; j < 8; ++j) h[j] = (f16)0.f;
    }
    *(f16x8*)&memh[e] = h;
  }
}

// ---- G1+NOV: g0 = relu(xh @ projW^T + b). 64x64 tile, BK=64, ring-3 (24 KB/buf).
// colPanel==0 blocks also compute novelty partials vs memh (r18-validated logic).
__global__ __launch_bounds__(256, 2) void gemm1_nov_kernel(
    const f16* __restrict__ A, const f16* __restrict__ wh,
    const f16* __restrict__ memh, const float* __restrict__ projB,
    f16* __restrict__ g0, float* __restrict__ novPart) {
  __shared__ __align__(16) char lds[3 * 24576];  // per buf: A 8K | B 8K | M 8K
  __shared__ float red[4];

  const int t = threadIdx.x, l = t & 63, w = t >> 6;
  const int wr = w >> 1, wc = w & 1;
  const int lr = l & 15, lk = l >> 4;
  int rowPanel, colPanel;
  remap_xcd(blockIdx.y * 128 + blockIdx.x, rowPanel, colPanel);
  const int rowBase = rowPanel * 64, colBase = colPanel * 64;
  const bool NOV = (colPanel == 0);

  auto stage = [&](int buf, int kt) {
    char* base = lds + buf * 24576;
    #pragma unroll
    for (int i = 0; i < 2; ++i) {
      const int o = i * 4096 + t * 16;
      const int row = o >> 7;                // 128 B per row (64 f16)
      const int sch = ((o >> 4) & 7) ^ (row & 7);
      llds16(A + (size_t)(rowBase + row) * BD + kt + sch * 8,
             base + i * 4096 + w * 1024);
      llds16(wh + (size_t)(colBase + row) * BD + kt + sch * 8,
             base + 8192 + i * 4096 + w * 1024);
    }
    if (NOV) {
      #pragma unroll
      for (int i = 0; i < 2; ++i) {
        const int o = i * 4096 + t * 16;
        const int row = o >> 7;
        const int sch = ((o >> 4) & 7) ^ (row & 7);
        llds16(memh + (size_t)row * BD + kt + sch * 8,
               base + 16384 + i * 4096 + w * 1024);
      }
    }
  };

  f32x4 acc[2][2], nacc[4];
  #pragma unroll
  for (int m = 0; m < 2; ++m)
    #pragma unroll
    for (int n = 0; n < 2; ++n) acc[m][n] = (f32x4){0.f,0.f,0.f,0.f};
  #pragma unroll
  for (int q = 0; q < 4; ++q) nacc[q] = (f32x4){0.f,0.f,0.f,0.f};
  float xsq[4] = {0.f, 0.f, 0.f, 0.f};
  float msq = 0.f;

  auto compute = [&](int buf) {
    const f16* Ab = (const f16*)(lds + buf * 24576);
    const f16* Bb = (const f16*)(lds + buf * 24576 + 8192);
    const f16* Mb = (const f16*)(lds + buf * 24576 + 16384);
    #pragma unroll
    for (int kk = 0; kk < 64; kk += 32) {
      const int ch = (kk >> 3) + lk;
      auto readA = [&](int r) -> f16x8 {
        return *(const f16x8*)&Ab[r * 64 + ((ch ^ (r & 7)) << 3)];
      };
      f16x8 af[2], bf[2];
      #pragma unroll
      for (int m = 0; m < 2; ++m) af[m] = readA(wr * 32 + m * 16 + lr);
      #pragma unroll
      for (int n = 0; n < 2; ++n) {
        const int row = wc * 32 + n * 16 + lr;
        bf[n] = *(const f16x8*)&Bb[row * 64 + ((ch ^ (row & 7)) << 3)];
      }
      __builtin_amdgcn_s_setprio(1);
      #pragma unroll
      for (int m = 0; m < 2; ++m)
        #pragma unroll
        for (int n = 0; n < 2; ++n)
          acc[m][n] = __builtin_amdgcn_mfma_f32_16x16x32_f16(af[m], bf[n], acc[m][n], 0, 0, 0);
      __builtin_amdgcn_s_setprio(0);
      if (NOV) {
        const int mrow = w * 16 + lr;
        f16x8 mf = *(const f16x8*)&Mb[mrow * 64 + ((ch ^ (mrow & 7)) << 3)];
        #pragma unroll
        for (int j = 0; j < 8; ++j) { float f = (float)mf[j]; msq += f * f; }
        f16x8 aq[4];                          // static indices (rule #20)
        if (wr == 0) {
          aq[0] = af[0]; aq[1] = af[1];
          aq[2] = readA(32 + lr); aq[3] = readA(48 + lr);
        } else {
          aq[0] = readA(lr); aq[1] = readA(16 + lr);
          aq[2] = af[0]; aq[3] = af[1];
        }
        #pragma unroll
        for (int q = 0; q < 4; ++q) {
          #pragma unroll
          for (int j = 0; j < 8; ++j) { float f = (float)aq[q][j]; xsq[q] += f * f; }
          nacc[q] = __builtin_amdgcn_mfma_f32_16x16x32_f16(aq[q], mf, nacc[q], 0, 0, 0);
        }
      }
    }
  };

  // ring-3, 1 stage in flight beyond current; counted vmcnt (never 0 mid-loop)
  stage(0, 0);
  stage(1, 64);
  #pragma unroll
  for (int t8 = 0; t8 < 8; ++t8) {
    if (t8 < 7) {
      if (NOV) asm volatile("s_waitcnt vmcnt(6)" ::: "memory");
      else     asm volatile("s_waitcnt vmcnt(4)" ::: "memory");
    } else {
      asm volatile("s_waitcnt vmcnt(0)" ::: "memory");
    }
    __builtin_amdgcn_s_barrier();            // tile t8 fully in LDS (all waves)
    if (t8 < 6) stage((t8 + 2) % 3, (t8 + 2) * 64);
    compute(t8 % 3);
    asm volatile("s_waitcnt lgkmcnt(0)" ::: "memory");
  }

  // novelty tail (r18-validated): reduce norms, sqrt-sum, per-rowPanel partial
  if (NOV) {
    msq += __shfl_xor(msq, 16, 64);
    msq += __shfl_xor(msq, 32, 64);
    #pragma unroll
    for (int q = 0; q < 4; ++q) {
      xsq[q] += __shfl_xor(xsq[q], 16, 64);
      xsq[q] += __shfl_xor(xsq[q], 32, 64);
    }
    const int mm = w * 16 + lr;
    float local = 0.f;
    if (mm < 50) {
      #pragma unroll
      for (int j = 0; j < 4; ++j) {
        const int r16 = lk * 4 + j;          // C/D row-in-16 = (lane>>4)*4 + j
        #pragma unroll
        for (int q = 0; q < 4; ++q) {
          const float xs = __shfl(xsq[q], r16, 64);
          float d = xs - 2.f * nacc[q][j] + msq;
          local += sqrtf(fmaxf(d, 0.f));
        }
      }
    }
    #pragma unroll
    for (int off = 32; off; off >>= 1) local += __shfl_down(local, off, 64);
    if (l == 0) red[w] = local;
    __syncthreads();
    if (t == 0) novPart[rowPanel] = red[0] + red[1] + red[2] + red[3];
  }

  // epilogue
  #pragma unroll
  for (int n = 0; n < 2; ++n) {
    const int col = colBase + wc * 32 + n * 16 + lr;
    const float bbv = projB[col];
    #pragma unroll
    for (int m = 0; m < 2; ++m) {
      #pragma unroll
      for (int j = 0; j < 4; ++j) {
        const int rowg = rowBase + wr * 32 + m * 16 + lk * 4 + j;
        g0[(size_t)rowg * BD + col] = (f16)fmaxf(acc[m][n][j] + bbv, 0.f);
      }
    }
  }
}

// ---- G2/G3: r12-proven ring-4 GEMM + XCD co-location remap ----
// PICK: 1 = ops_W[idx_a]; 2 = ops_W[idx_b] (block lid==0 finalizes novelty)
template <int PICK, int OUTF16>
__global__ __launch_bounds__(256, 2) void gemm_relu_kernel(
    const f16* __restrict__ A, const f16* __restrict__ Wall,
    const float* __restrict__ ball, const float* __restrict__ logits,
    void* __restrict__ Out, const float* __restrict__ novPart,
    float* __restrict__ novOut) {
  __shared__ __align__(16) char lds[4 * 16384];  // per buf: 8 KB A + 8 KB B

  const int t = threadIdx.x;
  const int l = t & 63;
  const int w = t >> 6;
  const int wr = w >> 1, wc = w & 1;
  const int lr = l & 15, lk = l >> 4;

  if (PICK == 2 && blockIdx.x == 0 && blockIdx.y == 0 && w == 0) {
    float s = novPart[l] + novPart[l + 64];      // 128 partials
    #pragma unroll
    for (int off = 32; off; off >>= 1) s += __shfl_down(s, off, 64);
    if (l == 0) novOut[0] = fminf(1.5f, s * (1.0f / (8192.0f * 50.0f)));
  }

  float l0 = logits[0], l1 = logits[1], l2 = logits[2];
  int ia = 0; float ba = l0;
  if (l1 > ba) { ba = l1; ia = 1; }
  if (l2 > ba) { ba = l2; ia = 2; }
  int widx;
  if (PICK == 1) {
    widx = ia;
  } else {
    int ib = 0; float bb2 = -3.4e38f;
    if (ia != 0)             { bb2 = l0; ib = 0; }
    if (ia != 1 && l1 > bb2) { bb2 = l1; ib = 1; }
    if (ia != 2 && l2 > bb2) { bb2 = l2; ib = 2; }
    widx = ib;
  }
  const f16* W = Wall + (size_t)widx * BD * BD;
  const float* bias = ball + widx * BD;

  int rowPanel, colPanel;
  remap_xcd(blockIdx.y * 128 + blockIdx.x, rowPanel, colPanel);
  const int rowBase = rowPanel * 64;
  const int colBase = colPanel * 64;

  f32x4 acc[2][2];
  #pragma unroll
  for (int m = 0; m < 2; ++m)
    #pragma unroll
    for (int n = 0; n < 2; ++n) acc[m][n] = (f32x4){0.f, 0.f, 0.f, 0.f};

  auto stage = [&](int buf, int kt) {
    f16* Ab = (f16*)(lds + buf * 16384);
    f16* Bb = (f16*)(lds + buf * 16384 + 8192);
    #pragma unroll
    for (int i = 0; i < 2; ++i) {
      const int o = i * 4096 + t * 16;
      const int row = o >> 7;                // 128 B per row (64 f16)
      const int sch = ((o >> 4) & 7) ^ (row & 7);
      llds16(A + (size_t)(rowBase + row) * BD + kt + sch * 8,
             (char*)Ab + i * 4096 + w * 1024);
      llds16(W + (size_t)(colBase + row) * BD + kt + sch * 8,
             (char*)Bb + i * 4096 + w * 1024);
    }
  };

  auto compute = [&](int buf) {
    const f16* Ab = (const f16*)(lds + buf * 16384);
    const f16* Bb = (const f16*)(lds + buf * 16384 + 8192);
    #pragma unroll
    for (int kk = 0; kk < 64; kk += 32) {
      const int ch = (kk >> 3) + lk;
      f16x8 af[2], bf[2];
      #pragma unroll
      for (int m = 0; m < 2; ++m) {
        const int row = wr * 32 + m * 16 + lr;
        af[m] = *(const f16x8*)&Ab[row * 64 + ((ch ^ (row & 7)) << 3)];
      }
      #pragma unroll
      for (int n = 0; n < 2; ++n) {
        const int row = wc * 32 + n * 16 + lr;
        bf[n] = *(const f16x8*)&Bb[row * 64 + ((ch ^ (row & 7)) << 3)];
      }
      __builtin_amdgcn_s_setprio(1);
      #pragma unroll
      for (int m = 0; m < 2; ++m)
        #pragma unroll
        for (int n = 0; n < 2; ++n)
          acc[m][n] = __builtin_amdgcn_mfma_f32_16x16x32_f16(af[m], bf[n], acc[m][n], 0, 0, 0);
      __builtin_amdgcn_s_setprio(0);
    }
  };

  stage(0, 0);
  stage(1, 64);
  stage(2, 128);
  #pragma unroll
  for (int t8 = 0; t8 < 8; ++t8) {
    if (t8 < 6)       asm volatile("s_waitcnt vmcnt(8)" ::: "memory");
    else if (t8 == 6) asm volatile("s_waitcnt vmcnt(4)" ::: "memory");
    else              asm volatile("s_waitcnt vmcnt(0)" ::: "memory");
    __builtin_amdgcn_s_barrier();
    if (t8 < 5) stage((t8 + 3) & 3, (t8 + 3) * 64);
    compute(t8 & 3);
    asm volatile("s_waitcnt lgkmcnt(0)" ::: "memory");
  }

  #pragma unroll
  for (int n = 0; n < 2; ++n) {
    const int col = colBase + wc * 32 + n * 16 + lr;
    const float bbv = bias[col];
    #pragma unroll
    for (int m = 0; m < 2; ++m) {
      #pragma unroll
      for (int j = 0; j < 4; ++j) {
        const int rowg = rowBase + wr * 32 + m * 16 + lk * 4 + j;
        float v = fmaxf(acc[m][n][j] + bbv, 0.f);
        if (OUTF16) ((f16*)Out)[(size_t)rowg * BD + col] = (f16)v;
        else        ((float*)Out)[(size_t)rowg * BD + col] = v;
      }
    }
  }
}

extern "C" void kernel_launch(void* const* d_in, const int* in_sizes, int n_in,
                              void* d_out, int out_size, void* d_ws, size_t ws_size,
                              hipStream_t stream) {
  const float* x      = (const float*)d_in[0];   // [8192,512]
  const float* memf   = (const float*)d_in[1];   // [50,512]
  const float* logits = (const float*)d_in[2];   // [3]
  const float* projW  = (const float*)d_in[3];   // [512,512]
  const float* projB  = (const float*)d_in[4];   // [512]
  const float* opsW   = (const float*)d_in[5];   // [3,512,512]
  const float* opsB   = (const float*)d_in[6];   // [3,512]
  float* out = (float*)d_out;                    // [8192*512 + 1]

  char* ws = (char*)d_ws;
  f16*   xh      = (f16*)(ws);                // 8 MB (reused as h1)
  f16*   g0      = (f16*)(ws + 8388608);      // 8 MB
  f16*   wh      = (f16*)(ws + 16777216);     // 2 MB: proj_W f16, then ops_W f16
  f16*   memh    = (f16*)(ws + 18874368);     // 64 KB (64x512 zero-padded)
  float* novPart = (float*)(ws + 18939904);   // 512 B (128 floats)

  prep_kernel<<<2576, 256, 0, stream>>>(x, projW, opsW, memf, xh, wh, memh);

  // G1+NOV: g0 = relu(xh @ projW^T + projB); colPanel==0 emits novelty partials
  gemm1_nov_kernel<<<dim3(128, 8), 256, 0, stream>>>(xh, wh, memh, projB, g0, novPart);
  // G2: h1 = relu(g0 @ Wa^T + ba)   (h1 overwrites xh)
  gemm_relu_kernel<1, 1><<<dim3(128, 8), 256, 0, stream>>>(
      g0, wh + 262144, opsB, logits, (void*)xh, novPart, out + 4194304);
  // G3: out = relu(h1 @ Wb^T + bb); finalizes novelty scalar
  gemm_relu_kernel<2, 0><<<dim3(128, 8), 256, 0, stream>>>(
      xh, wh + 262144, opsB, logits, (void*)out, novPart, out + 4194304);
}